// Round 4
// baseline (829.536 us; speedup 1.0000x reference)
//
#include <hip/hip_runtime.h>
#include <stdint.h>

#define NC   8
#define NK   4096
#define DD   128
#define NCLS 1000
#define NB   8192

// ---------------------------------------------------------------------------
// d_out byte layout during the run (out = 32,768,000 B):
//   [0,         8,388,608)  bimg : f16-hi codebook image, swizzled, 1MB per k
//   [8,388,608, 8,519,680)  csq  : f32 (-0.5*||c||^2), 8*4096
//   [8,519,680, 8,658,944)  stash: packed top-3 (2xu32) for b < 2176
//   rows b >= 2176 (= bm >= 17): gemm writes the 8B top-3 header DIRECTLY at
//   row start (bytes [b*4000 + k*8)) — those bytes are outside every region
//   gemm reads. reloc (single block, load-all-then-store) moves stash ->
//   headers for b < 2176. finish reads only its own row header, then
//   overwrites its full row. d_ws is never touched.
// ---------------------------------------------------------------------------
#define BIMG_B   0
#define CSQ_B    8388608
#define STASH_B  8519680
#define BCUT     2176

typedef _Float16 f16;
typedef f16   f16x8 __attribute__((ext_vector_type(8)));
typedef float f32x4 __attribute__((ext_vector_type(4)));

typedef const __attribute__((address_space(1))) unsigned int g_u32;
typedef __attribute__((address_space(3))) unsigned int l_u32;

__device__ __forceinline__ void gll16(const char* g, char* l) {
    __builtin_amdgcn_global_load_lds((g_u32*)g, (l_u32*)l, 16, 0, 0);
}

// XOR swizzle within an 8KB chunk: [32 rows][256B]; spreads ds_read_b128.
__device__ __forceinline__ int swz(int row, int kg) {
    return (row * 256 + kg * 16) ^ ((row & 7) << 4);
}

// strict top-3 insert (ascending-index insertion order keeps np-argmin ties)
__device__ __forceinline__ void ins3(float cv, int ci,
                                     float& v1, int& i1, float& v2, int& i2,
                                     float& v3, int& i3) {
    if (cv > v1) { v3 = v2; i3 = i2; v2 = v1; i2 = i1; v1 = cv; i1 = ci; }
    else if (cv > v2) { v3 = v2; i3 = i2; v2 = cv; i2 = ci; }
    else if (cv > v3) { v3 = cv; i3 = ci; }
}
// tie-aware variant for cross-lane merges (prefer lower index on equal)
__device__ __forceinline__ void ins3t(float cv, int ci,
                                      float& v1, int& i1, float& v2, int& i2,
                                      float& v3, int& i3) {
    const bool g1 = (cv > v1) || (cv == v1 && ci < i1);
    const bool g2 = (cv > v2) || (cv == v2 && ci < i2);
    const bool g3 = (cv > v3) || (cv == v3 && ci < i3);
    if (g1) { v3 = v2; i3 = i2; v2 = v1; i2 = i1; v1 = cv; i1 = ci; }
    else if (g2) { v3 = v2; i3 = i2; v2 = cv; i2 = ci; }
    else if (g3) { v3 = cv; i3 = ci; }
}

__device__ __forceinline__ void cvt8(const float4 v0, const float4 v1,
                                     f16x8& h, f16x8& l) {
    float vs[8] = {v0.x, v0.y, v0.z, v0.w, v1.x, v1.y, v1.z, v1.w};
#pragma unroll
    for (int i = 0; i < 8; ++i) {
        const float v = vs[i];
        const f16 hi = (f16)v;
        h[i] = hi;
        l[i] = (f16)((v - (float)hi) * 2048.0f);
    }
}

// ---------------------------------------------------------------------------
// Kernel 1: codebooks -> f16-hi swizzled image + csq (= -0.5*||c||^2, exact
// f32 from f32 inputs). Block: 64 codewords of one codebook.
// ---------------------------------------------------------------------------
__global__ __launch_bounds__(256) void prep_cb(const float* __restrict__ cb,
                                               char* __restrict__ outc) {
    const int k = blockIdx.y, t = threadIdx.x;
    const int col0 = blockIdx.x * 64;
    float* csq = (float*)(outc + CSQ_B);
#pragma unroll
    for (int j = 0; j < 4; ++j) {
        const int col = j * 16 + (t >> 4);   // [0,64)
        const int kg  = t & 15;
        const int colg = col0 + col;
        const float* p = cb + ((size_t)k * NK + colg) * DD + kg * 8;
        const float4 v0 = *(const float4*)p;
        const float4 v1 = *(const float4*)(p + 4);
        float vs[8] = {v0.x, v0.y, v0.z, v0.w, v1.x, v1.y, v1.z, v1.w};
        f16x8 h;
        float ss = 0.f;
#pragma unroll
        for (int i = 0; i < 8; ++i) {
            const float v = vs[i];
            ss += v * v;
            h[i] = (f16)v;
        }
#pragma unroll
        for (int m = 1; m < 16; m <<= 1) ss += __shfl_xor(ss, m, 16);
        if (kg == 0) csq[k * NK + colg] = -0.5f * ss;
        const int c = colg >> 5, r = colg & 31;
        *(f16x8*)(outc + BIMG_B + (size_t)k * 1048576 + c * 8192 + swz(r, kg)) = h;
    }
}

// ---------------------------------------------------------------------------
// One pipelined chunk step: counted vmcnt + raw barrier, issue chunk c+2,
// 16 MFMA (x-hi + x-lo vs c-hi), fused top-3 epilogue.
// ---------------------------------------------------------------------------
template <int W, bool ISS>
__device__ __forceinline__ void chunk_step(
    int c, int& bcur, int& bnx, char* lds, const char* gB,
    int w, int lane, int l15,
    const f16x8 (&Ah)[4], const f16x8 (&Al)[4], const int (&boff)[4][2],
    float (&rv1)[4], float (&rv2)[4], float (&rv3)[4],
    int (&ri1)[4], int (&ri2)[4], int (&ri3)[4]) {

    asm volatile("s_waitcnt vmcnt(%0)" :: "i"(W) : "memory");
    __builtin_amdgcn_s_barrier();

    if (ISS) {
        const char* src = gB + (size_t)(c + 2) * 8192 + w * 1024 + lane * 16;
        gll16(src, lds + bnx * 8192 + w * 1024 + lane * 16);
    }

    char* bufc = lds + bcur * 8192;
    const float* csqL = (const float*)(lds + 24576);
    const float cs0 = csqL[c * 32 + l15];
    const float cs1 = csqL[c * 32 + 16 + l15];
    f32x4 ah0 = (f32x4){cs0, cs0, cs0, cs0};
    f32x4 ah1 = (f32x4){cs1, cs1, cs1, cs1};
    f32x4 al0 = (f32x4){0.f, 0.f, 0.f, 0.f};
    f32x4 al1 = (f32x4){0.f, 0.f, 0.f, 0.f};

    __builtin_amdgcn_s_setprio(1);
#pragma unroll
    for (int kk = 0; kk < 4; ++kk) {
        const f16x8 bh0 = *(const f16x8*)(bufc + boff[kk][0]);
        const f16x8 bh1 = *(const f16x8*)(bufc + boff[kk][1]);
        ah0 = __builtin_amdgcn_mfma_f32_16x16x32_f16(Ah[kk], bh0, ah0, 0, 0, 0);
        ah1 = __builtin_amdgcn_mfma_f32_16x16x32_f16(Ah[kk], bh1, ah1, 0, 0, 0);
        al0 = __builtin_amdgcn_mfma_f32_16x16x32_f16(Al[kk], bh0, al0, 0, 0, 0);
        al1 = __builtin_amdgcn_mfma_f32_16x16x32_f16(Al[kk], bh1, al1, 0, 0, 0);
    }
    __builtin_amdgcn_s_setprio(0);

    const int col0 = c * 32 + l15;
#pragma unroll
    for (int q = 0; q < 4; ++q) {
        const float s0 = fmaf(al0[q], 4.8828125e-4f, ah0[q]);
        const float s1 = fmaf(al1[q], 4.8828125e-4f, ah1[q]);
        float cv, cw; int ci, cj;
        if (s1 > s0) { cv = s1; ci = col0 + 16; cw = s0; cj = col0; }
        else         { cv = s0; ci = col0;      cw = s1; cj = col0 + 16; }
        ins3(cv, ci, rv1[q], ri1[q], rv2[q], ri2[q], rv3[q], ri3[q]);
        // rare second insert: keeps the pair-min when it is top-3-worthy
        if (cw > rv3[q])
            ins3(cw, cj, rv1[q], ri1[q], rv2[q], ri2[q], rv3[q], ri3[q]);
    }
    bcur = (bcur == 2) ? 0 : bcur + 1;
    bnx  = (bnx  == 2) ? 0 : bnx  + 1;
}

// ---------------------------------------------------------------------------
// Kernel 2: distance GEMM (x split hi/lo vs c-hi) + per-lane top-3 ->
// merged global top-3 per (row,k). 512 thr, 8 waves x 16 rows, 128 chunks
// of 32 codewords, 3-buffer counted-vmcnt pipeline, csq in LDS.
// LDS 40KB. Grid 512 1-D: k = id&7 pins each codebook's image to one XCD L2.
// ---------------------------------------------------------------------------
__global__ __launch_bounds__(512, 4) void gemm_argmin(
    const float* __restrict__ x, char* __restrict__ outc) {
    __shared__ char lds[40960];
    const int t = threadIdx.x;
    const int lane = t & 63, w = t >> 6;
    const int k = blockIdx.x & 7, bm = blockIdx.x >> 3;
    const int l15 = lane & 15, l4 = lane >> 4;

    // csq -> LDS [24576, 40960)
    {
        const float4* cg = (const float4*)((const char*)outc + CSQ_B) + k * (NK / 4);
        float4* cl = (float4*)(lds + 24576);
        cl[t] = cg[t];
        cl[t + 512] = cg[t + 512];
    }

    // A fragments: row = bm*128 + w*16 + l15, k-slice (kk*4+l4)*8..+8
    f16x8 Ah[4], Al[4];
    {
        const float* xrow = x + (size_t)(bm * 128 + w * 16 + l15) * 1024 + k * DD;
#pragma unroll
        for (int kk = 0; kk < 4; ++kk) {
            const float* p = xrow + (kk * 4 + l4) * 8;
            cvt8(*(const float4*)p, *(const float4*)(p + 4), Ah[kk], Al[kk]);
        }
    }

    int boff[4][2];
#pragma unroll
    for (int kk = 0; kk < 4; ++kk) {
#pragma unroll
        for (int n = 0; n < 2; ++n)
            boff[kk][n] = swz(n * 16 + l15, kk * 4 + l4);
    }

    float rv1[4], rv2[4], rv3[4];
    int   ri1[4], ri2[4], ri3[4];
#pragma unroll
    for (int q = 0; q < 4; ++q) {
        rv1[q] = -3.402823466e38f; rv2[q] = -3.402823466e38f;
        rv3[q] = -3.402823466e38f;
        ri1[q] = 0; ri2[q] = 0; ri3[q] = 0;
    }

    __syncthreads();   // csq visible; drains A/csq vmem (vmcnt clean)

    const char* gB = (const char*)outc + BIMG_B + (size_t)k * 1048576;
    // prologue: issue chunks 0,1
#pragma unroll
    for (int cn = 0; cn < 2; ++cn)
        gll16(gB + (size_t)cn * 8192 + w * 1024 + lane * 16,
              lds + cn * 8192 + w * 1024 + lane * 16);

    int bcur = 0, bnx = 2;
#pragma unroll 1
    for (int c = 0; c < 126; ++c)
        chunk_step<1, true>(c, bcur, bnx, lds, gB, w, lane, l15,
                            Ah, Al, boff, rv1, rv2, rv3, ri1, ri2, ri3);
    chunk_step<1, false>(126, bcur, bnx, lds, gB, w, lane, l15,
                         Ah, Al, boff, rv1, rv2, rv3, ri1, ri2, ri3);
    chunk_step<0, false>(127, bcur, bnx, lds, gB, w, lane, l15,
                         Ah, Al, boff, rv1, rv2, rv3, ri1, ri2, ri3);

    // cross-lane merge over the 16 l15-lanes (disjoint column residues)
#pragma unroll
    for (int m = 1; m < 16; m <<= 1) {
#pragma unroll
        for (int q = 0; q < 4; ++q) {
            const float ov1 = __shfl_xor(rv1[q], m, 16);
            const int   oi1 = __shfl_xor(ri1[q], m, 16);
            const float ov2 = __shfl_xor(rv2[q], m, 16);
            const int   oi2 = __shfl_xor(ri2[q], m, 16);
            const float ov3 = __shfl_xor(rv3[q], m, 16);
            const int   oi3 = __shfl_xor(ri3[q], m, 16);
            ins3t(ov1, oi1, rv1[q], ri1[q], rv2[q], ri2[q], rv3[q], ri3[q]);
            ins3t(ov2, oi2, rv1[q], ri1[q], rv2[q], ri2[q], rv3[q], ri3[q]);
            ins3t(ov3, oi3, rv1[q], ri1[q], rv2[q], ri2[q], rv3[q], ri3[q]);
        }
    }
    // write packed top-3: 8B per (row,k). Block-uniform target (bm>=17 ->
    // direct header; else stash).
    if (l15 == 0) {
#pragma unroll
        for (int q = 0; q < 4; ++q) {
            const int b = bm * 128 + w * 16 + l4 * 4 + q;
            uint2 pkv;
            pkv.x = (uint32_t)ri1[q] | ((uint32_t)ri2[q] << 16);
            pkv.y = (uint32_t)ri3[q];
            char* base = (bm >= 17)
                ? outc + (size_t)b * 4000 + k * 8
                : outc + STASH_B + ((size_t)b * 8 + k) * 8;
            *(uint2*)base = pkv;
        }
    }
}

// ---------------------------------------------------------------------------
// Kernel 3: single-block reloc of stash -> row headers for b < 2176.
// Load-all-to-registers, barrier, store-all: race-free even where header
// writes land inside the stash region itself.
// ---------------------------------------------------------------------------
__global__ __launch_bounds__(1024) void reloc(char* __restrict__ outc) {
    const int t = threadIdx.x;
    const uint2* stash = (const uint2*)(outc + STASH_B);
    uint2 vals[17];
#pragma unroll
    for (int j = 0; j < 17; ++j) vals[j] = stash[j * 1024 + t];
    __syncthreads();
#pragma unroll
    for (int j = 0; j < 17; ++j) {
        const int e = j * 1024 + t;       // [0, 17408)
        const int b = e >> 3, k = e & 7;
        *(uint2*)(outc + (size_t)b * 4000 + k * 8) = vals[j];
    }
}

// ---------------------------------------------------------------------------
// Kernel 4: per batch row — exact f64 re-rank of the 3 candidates, then
// gather 8 table rows and sum. Reads only its own header; overwrites row.
// ---------------------------------------------------------------------------
__global__ __launch_bounds__(256) void finish(const float* __restrict__ x,
                                              const float* __restrict__ cb,
                                              const float* __restrict__ tables,
                                              float* __restrict__ out) {
    const int b = blockIdx.x, t = threadIdx.x;
    const int lane = t & 63, w = t >> 6;
    __shared__ uint2 hdr_s[8];
    __shared__ int rows_s[8];
    if (t < 8) hdr_s[t] = *(const uint2*)((const char*)out + (size_t)b * 4000 + t * 8);
    __syncthreads();
#pragma unroll
    for (int kq = 0; kq < 2; ++kq) {
        const int k = w * 2 + kq;
        const uint2 h = hdr_s[k];
        const int i1 = (int)(h.x & 0xFFFFu);
        const int i2 = (int)(h.x >> 16);
        const int i3 = (int)(h.y & 0xFFFFu);
        const double x0 = (double)x[(size_t)b * 1024 + k * DD + lane];
        const double x1 = (double)x[(size_t)b * 1024 + k * DD + 64 + lane];
        const float* cbk = cb + (size_t)k * NK * DD;
        double d[3];
        const int idx[3] = {i1, i2, i3};
#pragma unroll
        for (int j = 0; j < 3; ++j) {
            const float* cp = cbk + (size_t)idx[j] * DD;
            const double e0 = (double)cp[lane] - x0;
            const double e1 = (double)cp[64 + lane] - x1;
            double dv = e0 * e0 + e1 * e1;
#pragma unroll
            for (int m = 32; m >= 1; m >>= 1) dv += __shfl_xor(dv, m, 64);
            d[j] = dv;
        }
        if (lane == 0) {
            double bd = d[0]; int bi = idx[0];
            if (d[1] < bd || (d[1] == bd && idx[1] < bi)) { bd = d[1]; bi = idx[1]; }
            if (d[2] < bd || (d[2] == bd && idx[2] < bi)) { bd = d[2]; bi = idx[2]; }
            rows_s[k] = bi;
        }
    }
    __syncthreads();
    if (t < 250) {
        float4 acc = {0.f, 0.f, 0.f, 0.f};
#pragma unroll
        for (int k = 0; k < NC; ++k) {
            const float4 v =
                *((const float4*)(tables + ((size_t)k * NK + rows_s[k]) * NCLS) + t);
            acc.x += v.x; acc.y += v.y; acc.z += v.z; acc.w += v.w;
        }
        *((float4*)(out + (size_t)b * NCLS) + t) = acc;
    }
}

extern "C" void kernel_launch(void* const* d_in, const int* in_sizes, int n_in,
                              void* d_out, int out_size, void* d_ws, size_t ws_size,
                              hipStream_t stream) {
    const float* x      = (const float*)d_in[0];
    const float* cb     = (const float*)d_in[1];
    const float* tables = (const float*)d_in[2];
    float* out = (float*)d_out;
    char* outc = (char*)d_out;

    prep_cb<<<dim3(64, NC), 256, 0, stream>>>(cb, outc);
    gemm_argmin<<<512, 512, 0, stream>>>(x, outc);
    reloc<<<1, 1024, 0, stream>>>(outc);
    finish<<<NB, 256, 0, stream>>>(x, cb, tables, out);
}